// Round 2
// baseline (139.624 us; speedup 1.0000x reference)
//
#include <hip/hip_runtime.h>

typedef _Float16 half8 __attribute__((ext_vector_type(8)));
typedef float floatx4 __attribute__((ext_vector_type(4)));
typedef int intx4 __attribute__((ext_vector_type(4)));
typedef int intx8 __attribute__((ext_vector_type(8)));
typedef __attribute__((address_space(1))) const void gvoid;
typedef __attribute__((address_space(3))) void svoid;

#define SCALE_POS 2.0f
#define SCALE_NEG 40.0f
#define THRESH 0.5f
#define MARGIN 0.1f
#define EPSV 1e-5f

// order-preserving float<->uint map (no NaNs present)
__device__ __forceinline__ unsigned f2ord(float f) {
    unsigned u = __float_as_uint(f);
    return (u & 0x80000000u) ? ~u : (u | 0x80000000u);
}
__device__ __forceinline__ float ord2f(unsigned e) {
    unsigned v = (e & 0x80000000u) ? (e & 0x7fffffffu) : ~e;
    return __uint_as_float(v);
}

#define ORD_POS_INF 0xff800000u   // f2ord(+inf)
#define ORD_NEG_INF 0x007fffffu   // f2ord(-inf)

// ---- kernel 1: fp32 -> fp8 e4m3 (OCP, RNE via HW cvt) + stat/counter init ----
__global__ void k_init(const float* __restrict__ feats,
                       unsigned char* __restrict__ f8,
                       unsigned* __restrict__ minp, unsigned* __restrict__ maxn,
                       float* __restrict__ psum, float* __restrict__ nsum,
                       unsigned* __restrict__ cnts,
                       int total4, int B) {
    int i = blockIdx.x * blockDim.x + threadIdx.x;
    if (i < total4) {
        float4 v = ((const float4*)feats)[i];
        int w = 0;
        w = __builtin_amdgcn_cvt_pk_fp8_f32(v.x, v.y, w, false);  // bytes 0,1
        w = __builtin_amdgcn_cvt_pk_fp8_f32(v.z, v.w, w, true);   // bytes 2,3
        ((int*)f8)[i] = w;
    }
    if (i < B) {
        minp[i] = ORD_POS_INF;
        maxn[i] = ORD_NEG_INF;
        psum[i] = 0.f;
        nsum[i] = 0.f;
    }
    if (i < 2048) cnts[i] = 0;   // top @0; stripe s @ (1+s)*32
}

// =====================================================================
// kernel 2 (R18): MX-fp8 symmetric GEMM over 128x64 HALF-tiles.
// 1056 blocks x 128 thr (2 waves, each a full 64x64 worker, 16
// mfma_scale_f32_16x16x128_f8f6f4 per K=128 iter, unity E8M0 scales).
//
// CHANGE vs R17 (48.4 us, regressed vs R14's 44.7): the dbuf pipeline
// was defeated by __syncthreads' implicit vmcnt(0) drain (guide §5:
// the m97-ceiling mechanism; R16 found the same null). R18 keeps the
// double buffer but uses RAW s_barrier + hand-counted vmcnt (T3+T4,
// m218: counted-vs-drain0 +38-73%):
//   per half-step: { STAGE(other buf, next tile)   // +12 loads
//                    s_waitcnt vmcnt(12)           // cur tile landed,
//                                                  // next 12 stay in flight
//                    s_barrier; COMPUTE(cur); s_barrier }
// The prefetch is never drained inside the loop; stage latency hides
// under the previous tile's ds_read+MFMA. Hazards: per-wave vmcnt(12)
// + barrier => all waves' stages landed (each wave waits its OWN 12);
// ds_reads retire before their consumer MFMAs, hence before the
// trailing barrier that precedes the buffer's next overwrite (WAR ok);
// labels staging fully drained by one pre-loop __syncthreads so no
// stray vmem ops perturb the count; x2-unrolled loop keeps buffer
// indices and waitcnt immediates compile-time (rule #20).
// Epilogue needs vmcnt(0)+lgkmcnt covered: final half-step uses
// vmcnt(0) since nothing is prefetched past the last tile.
// =====================================================================
__global__ void __launch_bounds__(128, 2)
k_gemm_h(const unsigned char* __restrict__ f8,
         const int* __restrict__ labels,
         unsigned* __restrict__ minp_ord,
         unsigned* __restrict__ maxn_ord,
         _Float16* __restrict__ simh,
         int D, int nb) {      // D = 1024 elements = 1024 bytes/row
    // buffer b: As = S[b][0..16K), Bs = S[b][16K..24K)
    __shared__ __align__(16) unsigned char S[2][24 * 1024];   // 48 KB
    __shared__ int labR[128], labC[64];

    const int bid = blockIdx.x;
    int t = bid >> 1;
    const int h = bid & 1;
    int rb = 0, rem = t;
    while (rem >= nb - rb) { rem -= nb - rb; ++rb; }
    const int cb = rb + rem;
    const int rowBase = rb * 128;
    const int colBase = cb * 128 + h * 64;

    const int tid = threadIdx.x;        // 0..127
    const int lane = tid & 63;
    const int wave = tid >> 6;          // 0..1 : row half (64 rows each)
    const int q = lane >> 4;
    const int cIn = lane & 15;

    labR[tid] = labels[rowBase + tid];
    if (tid < 64) labC[tid] = labels[colBase + tid];

    // staging: 24 chunks of 1KB (8 rows x 128B). Wave handles 12.
    // lane i: subrow = i>>3, physical block = i&7, logical = (i&7)^(i>>3)
    const int subrow = lane >> 3;
    const int swz = (lane & 7) ^ subrow;     // logical 16B-block index
    const unsigned char* gP[12];
    unsigned char* lP[12];                   // buffer-0 LDS dst; buf1 = +24576
#pragma unroll
    for (int j = 0; j < 12; ++j) {
        const int c = wave * 12 + j;
        const int grow = (c < 16) ? (rowBase + c * 8 + subrow)
                                  : (colBase + (c - 16) * 8 + subrow);
        gP[j] = f8 + (size_t)grow * D + swz * 16;
        lP[j] = S[0] + c * 1024 + lane * 16;   // c>=16 lands in Bs region
    }

    // fragment LDS byte offsets within one 24KB buffer:
    // row r, 32B k-group q = logical blocks 2q,2q+1; physical p = blk ^ (r&7)
    int aOff0[4], aOff1[4], bOff0[4], bOff1[4];
#pragma unroll
    for (int i = 0; i < 4; ++i) {
        const int rA = wave * 64 + i * 16 + cIn;
        aOff0[i] = rA * 128 + ((2 * q) ^ (rA & 7)) * 16;
        aOff1[i] = rA * 128 + ((2 * q + 1) ^ (rA & 7)) * 16;
        const int rB = i * 16 + cIn;
        bOff0[i] = 16384 + rB * 128 + ((2 * q) ^ (rB & 7)) * 16;
        bOff1[i] = 16384 + rB * 128 + ((2 * q + 1) ^ (rB & 7)) * 16;
    }

    floatx4 acc[4][4] = {};

#define STAGE(buf, kOff)                                                       \
    {                                                                          \
        _Pragma("unroll")                                                      \
        for (int j = 0; j < 12; ++j)                                           \
            __builtin_amdgcn_global_load_lds((gvoid*)(gP[j] + (kOff)),         \
                                             (svoid*)(lP[j] + (buf) * 24576), \
                                             16, 0, 0);                        \
    }

#define COMPUTE(buf)                                                           \
    {                                                                          \
        const unsigned char* Sb = S[0] + (buf) * 24576;                        \
        intx8 a[4], b[4];                                                      \
        _Pragma("unroll")                                                      \
        for (int i = 0; i < 4; ++i) {                                          \
            intx4 lo = *(const intx4*)(Sb + aOff0[i]);                         \
            intx4 hi = *(const intx4*)(Sb + aOff1[i]);                         \
            a[i] = __builtin_shufflevector(lo, hi, 0, 1, 2, 3, 4, 5, 6, 7);    \
        }                                                                      \
        _Pragma("unroll")                                                      \
        for (int i = 0; i < 4; ++i) {                                          \
            intx4 lo = *(const intx4*)(Sb + bOff0[i]);                         \
            intx4 hi = *(const intx4*)(Sb + bOff1[i]);                         \
            b[i] = __builtin_shufflevector(lo, hi, 0, 1, 2, 3, 4, 5, 6, 7);    \
        }                                                                      \
        _Pragma("unroll")                                                      \
        for (int i = 0; i < 4; ++i)                                            \
            _Pragma("unroll")                                                  \
            for (int j2 = 0; j2 < 4; ++j2)                                     \
                acc[i][j2] = __builtin_amdgcn_mfma_scale_f32_16x16x128_f8f6f4( \
                    a[i], b[j2], acc[i][j2], 0, 0,                             \
                    0, 0x7f7f7f7f, 0, 0x7f7f7f7f);                             \
    }

    const int KT = D >> 7;               // 8 iters of K=128 (even)

    // drain labels loads + make labR/labC visible; clean vmcnt slate
    __syncthreads();

    // prologue: tile 0 -> buf0 (12 loads in flight)
    STAGE(0, 0);

    for (int kt = 0; kt < KT; kt += 2) {
        // --- half-step A: compute tile kt from buf0, prefetch kt+1 -> buf1 ---
        if (kt + 1 < KT) {
            STAGE(1, (kt + 1) << 7);                               // out: 24
            asm volatile("s_waitcnt vmcnt(12)" ::: "memory");      // tile kt in
        } else {
            asm volatile("s_waitcnt vmcnt(0)" ::: "memory");
        }
        __builtin_amdgcn_s_barrier();
        COMPUTE(0);
        __builtin_amdgcn_s_barrier();   // all waves done reading buf0

        // --- half-step B: compute tile kt+1 from buf1, prefetch kt+2 -> buf0 ---
        if (kt + 2 < KT) {
            STAGE(0, (kt + 2) << 7);                               // out: 24
            asm volatile("s_waitcnt vmcnt(12)" ::: "memory");      // tile kt+1 in
        } else {
            asm volatile("s_waitcnt vmcnt(0)" ::: "memory");       // last tile
        }
        __builtin_amdgcn_s_barrier();
        COMPUTE(1);
        __builtin_amdgcn_s_barrier();   // all waves done reading buf1
    }

#undef STAGE
#undef COMPUTE

    int rLabv[16];
#pragma unroll
    for (int mi = 0; mi < 4; ++mi)
#pragma unroll
        for (int rr = 0; rr < 4; ++rr)
            rLabv[mi * 4 + rr] = labR[wave * 64 + mi * 16 + q * 4 + rr];
    int cLabv[4];
#pragma unroll
    for (int ni = 0; ni < 4; ++ni)
        cLabv[ni] = labC[ni * 16 + cIn];

    // ---- fp16 store: thread-major, 64 contiguous halves (R13 layout) ----
    {
        half8* dst = (half8*)(simh + (size_t)bid * 8192 + (size_t)tid * 64);
#pragma unroll
        for (int mi = 0; mi < 4; ++mi) {
            half8 h0, h1;
#pragma unroll
            for (int ni = 0; ni < 2; ++ni)
#pragma unroll
                for (int rr = 0; rr < 4; ++rr) {
                    h0[ni * 4 + rr] = (_Float16)acc[mi][ni][rr];
                    h1[ni * 4 + rr] = (_Float16)acc[mi][ni + 2][rr];
                }
            dst[mi * 2] = h0;
            dst[mi * 2 + 1] = h1;
        }
    }

    // ---- row stats ----
#pragma unroll
    for (int mi = 0; mi < 4; ++mi)
#pragma unroll
        for (int rr = 0; rr < 4; ++rr) {
            const int rLoc = wave * 64 + mi * 16 + q * 4 + rr;
            const int rLab = rLabv[mi * 4 + rr];
            float vmin = 1e30f, vmax = -1e30f;
#pragma unroll
            for (int ni = 0; ni < 4; ++ni) {
                float s = acc[mi][ni][rr];
                if (rLab == cLabv[ni]) {
                    if (s < 1.0f - EPSV) vmin = fminf(vmin, s);
                } else {
                    vmax = fmaxf(vmax, s);
                }
            }
#pragma unroll
            for (int off = 8; off; off >>= 1) {
                vmin = fminf(vmin, __shfl_xor(vmin, off, 16));
                vmax = fmaxf(vmax, __shfl_xor(vmax, off, 16));
            }
            if (cIn == 0) {
                if (vmin < 1e30f) atomicMin(&minp_ord[rowBase + rLoc], f2ord(vmin));
                if (vmax > -1e30f) atomicMax(&maxn_ord[rowBase + rLoc], f2ord(vmax));
            }
        }

    // ---- col stats via symmetry (off-diagonal tiles only) ----
    if (rb != cb) {
#pragma unroll
        for (int ni = 0; ni < 4; ++ni) {
            const int cLab = cLabv[ni];
            float vmin = 1e30f, vmax = -1e30f;
#pragma unroll
            for (int mi = 0; mi < 4; ++mi)
#pragma unroll
                for (int rr = 0; rr < 4; ++rr) {
                    float s = acc[mi][ni][rr];
                    if (rLabv[mi * 4 + rr] == cLab) {
                        if (s < 1.0f - EPSV) vmin = fminf(vmin, s);
                    } else {
                        vmax = fmaxf(vmax, s);
                    }
                }
            vmin = fminf(vmin, __shfl_xor(vmin, 16, 64));
            vmin = fminf(vmin, __shfl_xor(vmin, 32, 64));
            vmax = fmaxf(vmax, __shfl_xor(vmax, 16, 64));
            vmax = fmaxf(vmax, __shfl_xor(vmax, 32, 64));
            if (q == 0) {
                const int cLoc = ni * 16 + cIn;
                if (vmin < 1e30f) atomicMin(&minp_ord[colBase + cLoc], f2ord(vmin));
                if (vmax > -1e30f) atomicMax(&maxn_ord[colBase + cLoc], f2ord(vmax));
            }
        }
    }
}

// =====================================================================
// kernel 3 (unchanged R13/R14): pass 2, 528 blocks x 256 threads +
// fused final reduction behind the hierarchical RELAXED done-counter.
// =====================================================================
__global__ void __launch_bounds__(256)
k_sum2f(const _Float16* __restrict__ simh,
        const int* __restrict__ labels,
        const unsigned* __restrict__ minp_ord,
        const unsigned* __restrict__ maxn_ord,
        float* __restrict__ psum, float* __restrict__ nsum,
        unsigned* __restrict__ cnts,   // top @0; stripe s @ (1+s)*32
        float* __restrict__ out,
        int nb, int B, int NT) {
    __shared__ int labR[128], labC[128];
    __shared__ float mpR[128], mnR[128], mpC[128], mnC[128];
    __shared__ float red[4];
    __shared__ unsigned lastflag;

    int t = blockIdx.x;
    int rb = 0, rem = t;
    while (rem >= nb - rb) { rem -= nb - rb; ++rb; }
    const int cb = rb + rem;
    const int rowBase = rb * 128;

    const int tid = threadIdx.x;
    const int sub = tid >> 7;
    const int stid = tid & 127;
    const int wave = stid >> 6;
    const int lane = tid & 63;
    const int q = lane >> 4;
    const int cIn = lane & 15;
    const int colBase = cb * 128 + sub * 64;

    if (tid < 128) {
        labR[tid] = labels[rowBase + tid];
        mpR[tid] = ord2f(minp_ord[rowBase + tid]) - MARGIN;   // neg kept if s > this
        mnR[tid] = ord2f(maxn_ord[rowBase + tid]) + MARGIN;   // pos kept if s < this
    } else {
        const int j = tid - 128;
        labC[j] = labels[cb * 128 + j];
        mpC[j] = ord2f(minp_ord[cb * 128 + j]) - MARGIN;
        mnC[j] = ord2f(maxn_ord[cb * 128 + j]) + MARGIN;
    }
    __syncthreads();

    int cLabv[4];
    float mpCv[4], mnCv[4];
#pragma unroll
    for (int ni = 0; ni < 4; ++ni) {
        const int j = sub * 64 + ni * 16 + cIn;
        cLabv[ni] = labC[j];
        mpCv[ni] = mpC[j];
        mnCv[ni] = mnC[j];
    }

    const half8* src = (const half8*)(simh + (size_t)(2 * t + sub) * 8192 + (size_t)stid * 64);
    half8 hv[8];
#pragma unroll
    for (int v = 0; v < 8; ++v) hv[v] = src[v];

    float cps[4] = {}, cns[4] = {};
    const bool offd = (rb != cb);

#pragma unroll
    for (int mi = 0; mi < 4; ++mi)
#pragma unroll
        for (int rr = 0; rr < 4; ++rr) {
            const int rLoc = wave * 64 + mi * 16 + q * 4 + rr;
            const int rLab = labR[rLoc];
            const float gateN = mpR[rLoc];
            const float gateP = mnR[rLoc];
            float rp = 0.f, rn = 0.f;
#pragma unroll
            for (int ni = 0; ni < 4; ++ni) {
                const int idx = mi * 16 + ni * 4 + rr;
                const float s = (float)hv[idx >> 3][idx & 7];
                if (rLab == cLabv[ni]) {
                    if (s < 1.0f - EPSV) {
                        float ev = __expf(-SCALE_POS * (s - THRESH));
                        if (s < gateP) rp += ev;
                        if (offd && s < mnCv[ni]) cps[ni] += ev;
                    }
                } else {
                    float ev = __expf(SCALE_NEG * (s - THRESH));
                    if (s > gateN) rn += ev;
                    if (offd && s > mpCv[ni]) cns[ni] += ev;
                }
            }
#pragma unroll
            for (int off = 8; off; off >>= 1) {
                rp += __shfl_xor(rp, off, 16);
                rn += __shfl_xor(rn, off, 16);
            }
            if (cIn == 0) {
                if (rp != 0.f) atomicAdd(&psum[rowBase + rLoc], rp);
                if (rn != 0.f) atomicAdd(&nsum[rowBase + rLoc], rn);
            }
        }
    if (offd) {
#pragma unroll
        for (int ni = 0; ni < 4; ++ni) {
            cps[ni] += __shfl_xor(cps[ni], 16, 64);
            cps[ni] += __shfl_xor(cps[ni], 32, 64);
            cns[ni] += __shfl_xor(cns[ni], 16, 64);
            cns[ni] += __shfl_xor(cns[ni], 32, 64);
            if (q == 0) {
                const int cLoc = ni * 16 + cIn;
                if (cps[ni] != 0.f) atomicAdd(&psum[colBase + cLoc], cps[ni]);
                if (cns[ni] != 0.f) atomicAdd(&nsum[colBase + cLoc], cns[ni]);
            }
        }
    }

    // ---- hierarchical done-counter (all RELAXED — no fences) ----
    __syncthreads();
    if (tid == 0) {
        const unsigned stripe = (unsigned)blockIdx.x & 31u;
        const unsigned stripe_target = (unsigned)((NT - (int)stripe + 31) / 32);
        unsigned prev = __hip_atomic_fetch_add(&cnts[(1 + stripe) * 32], 1u,
                                               __ATOMIC_RELAXED, __HIP_MEMORY_SCOPE_AGENT);
        unsigned lf = 0u;
        if (prev == stripe_target - 1u) {
            unsigned ptop = __hip_atomic_fetch_add(&cnts[0], 1u,
                                                   __ATOMIC_RELAXED, __HIP_MEMORY_SCOPE_AGENT);
            lf = (ptop == 31u) ? 1u : 0u;
        }
        lastflag = lf;
    }
    __syncthreads();
    if (lastflag) {
        float a = 0.f;
        for (int i = tid; i < B; i += 256) {
            float pv = atomicAdd(&psum[i], 0.0f);   // coherent returning atomic
            float nv = atomicAdd(&nsum[i], 0.0f);
            if (pv > 0.f && nv > 0.f)
                a += log1pf(pv) * (1.0f / SCALE_POS) + log1pf(nv) * (1.0f / SCALE_NEG);
        }
#pragma unroll
        for (int off = 32; off; off >>= 1) a += __shfl_down(a, off, 64);
        if ((tid & 63) == 0) red[tid >> 6] = a;
        __syncthreads();
        if (tid == 0) out[0] = (red[0] + red[1] + red[2] + red[3]) / (float)B;
    }
}

extern "C" void kernel_launch(void* const* d_in, const int* in_sizes, int n_in,
                              void* d_out, int out_size, void* d_ws, size_t ws_size,
                              hipStream_t stream) {
    const float* feats = (const float*)d_in[0];
    const int* labels = (const int*)d_in[1];
    const int B = in_sizes[1];            // 4096
    const int D = in_sizes[0] / B;        // 1024
    const int nb = B / 128;               // 32
    const int NT = nb * (nb + 1) / 2;     // 528
    const int NH = NT * 2;                // 1056 half-tiles
    const int total4 = B * D / 4;

    char* ws = (char*)d_ws;
    unsigned char* f8 = (unsigned char*)ws;
    size_t off = (size_t)B * D;           // 4 MB fp8
    unsigned* minp = (unsigned*)(ws + off); off += (size_t)B * 4;
    unsigned* maxn = (unsigned*)(ws + off); off += (size_t)B * 4;
    float* psum = (float*)(ws + off); off += (size_t)B * 4;
    float* nsum = (float*)(ws + off); off += (size_t)B * 4;
    unsigned* cnts = (unsigned*)(ws + off); off += 8192;  // 2048 u32, zeroed by k_init
    _Float16* simh = (_Float16*)(ws + ((off + 255) & ~(size_t)255));
    float* outp = (float*)d_out;

    k_init<<<(total4 + 255) / 256, 256, 0, stream>>>(feats, f8, minp, maxn,
                                                     psum, nsum, cnts, total4, B);

    // 1056 blocks x 128 thr — MX-fp8 K=128 GEMM, counted-vmcnt dbuf (R18)
    k_gemm_h<<<NH, 128, 0, stream>>>(f8, labels, minp, maxn, simh, D, nb);

    // 528 blocks x 256 thr, hierarchical relaxed done-counter
    k_sum2f<<<NT, 256, 0, stream>>>(simh, labels, minp, maxn, psum, nsum,
                                    cnts, outp, nb, B, NT);
}

// Round 3
// 138.512 us; speedup vs baseline: 1.0080x; 1.0080x over previous
//
#include <hip/hip_runtime.h>

typedef _Float16 half8 __attribute__((ext_vector_type(8)));
typedef float floatx4 __attribute__((ext_vector_type(4)));
typedef int intx4 __attribute__((ext_vector_type(4)));
typedef int intx8 __attribute__((ext_vector_type(8)));
typedef __attribute__((address_space(1))) const void gvoid;
typedef __attribute__((address_space(3))) void svoid;

#define SCALE_POS 2.0f
#define SCALE_NEG 40.0f
#define THRESH 0.5f
#define MARGIN 0.1f
#define EPSV 1e-5f

// order-preserving float<->uint map (no NaNs present)
__device__ __forceinline__ unsigned f2ord(float f) {
    unsigned u = __float_as_uint(f);
    return (u & 0x80000000u) ? ~u : (u | 0x80000000u);
}
__device__ __forceinline__ float ord2f(unsigned e) {
    unsigned v = (e & 0x80000000u) ? (e & 0x7fffffffu) : ~e;
    return __uint_as_float(v);
}

#define ORD_POS_INF 0xff800000u   // f2ord(+inf)
#define ORD_NEG_INF 0x007fffffu   // f2ord(-inf)

// ---- kernel 1: fp32 -> fp8 e4m3 (OCP, RNE via HW cvt) + stat/counter init ----
__global__ void k_init(const float* __restrict__ feats,
                       unsigned char* __restrict__ f8,
                       unsigned* __restrict__ minp, unsigned* __restrict__ maxn,
                       float* __restrict__ psum, float* __restrict__ nsum,
                       unsigned* __restrict__ cnts,
                       int total4, int B) {
    int i = blockIdx.x * blockDim.x + threadIdx.x;
    if (i < total4) {
        float4 v = ((const float4*)feats)[i];
        int w = 0;
        w = __builtin_amdgcn_cvt_pk_fp8_f32(v.x, v.y, w, false);  // bytes 0,1
        w = __builtin_amdgcn_cvt_pk_fp8_f32(v.z, v.w, w, true);   // bytes 2,3
        ((int*)f8)[i] = w;
    }
    if (i < B) {
        minp[i] = ORD_POS_INF;
        maxn[i] = ORD_NEG_INF;
        psum[i] = 0.f;
        nsum[i] = 0.f;
    }
    if (i < 2048) cnts[i] = 0;   // top @0; stripe s @ (1+s)*32
}

// =====================================================================
// kernel 2 (R19): MX-fp8 symmetric GEMM over FULL 128x128 tiles.
// 528 blocks x 256 thr (4 waves in a 2x2 grid of 64x64 sub-tiles).
//
// Rationale vs R14/R17/R18 (all ~45-48 us, MfmaUtil ~7%): pipeline
// restructurings were measured-null, so the K-loop sync is not the
// bottleneck. Wave-lifetime arithmetic shows ~4500 idle cyc per
// K-step — memory-system congestion/locality. R19 attacks demand:
//  * A-panel staged ONCE per tile (was twice across the 2 half-tile
//    blocks): staged DMA 202 MB -> 135 MB, instruction count -33%.
//  * Bijective XCD swizzle (528 = 8*66): consecutive tiles of one XCD
//    share A-panels in that XCD's L2 instead of thrashing L3 (T1).
//  * 4-wave blocks, 33 KB LDS single-buffer -> 4 blocks/CU = 16
//    waves/CU cap (was 6); halves block count.
// Loop shape = R14's proven single-buffer 2-sync (pipelining null).
// simh layout per 64-col half identical to R13/R14 (hb = 2t+wc,
// tid' = wr*64+lane), so k_sum2f is untouched.
// =====================================================================
__global__ void __launch_bounds__(256, 4)
k_gemm_h(const unsigned char* __restrict__ f8,
         const int* __restrict__ labels,
         unsigned* __restrict__ minp_ord,
         unsigned* __restrict__ maxn_ord,
         _Float16* __restrict__ simh,
         int D, int nb) {      // D = 1024 elements = 1024 bytes/row
    __shared__ __align__(16) unsigned char As[128 * 128];  // 16 KB
    __shared__ __align__(16) unsigned char Bs[128 * 128];  // 16 KB
    __shared__ int labR[128], labC[128];

    // bijective XCD-aware swizzle: 528 tiles = 8 XCDs x 66
    const int bid0 = blockIdx.x;
    const int t = (bid0 & 7) * 66 + (bid0 >> 3);
    int rb = 0, rem = t;
    while (rem >= nb - rb) { rem -= nb - rb; ++rb; }
    const int cb = rb + rem;
    const int rowBase = rb * 128;
    const int colBase = cb * 128;

    const int tid = threadIdx.x;        // 0..255
    const int lane = tid & 63;
    const int wave = tid >> 6;          // 0..3
    const int wr = wave >> 1;           // row half of output tile
    const int wc = wave & 1;            // col half of output tile
    const int q = lane >> 4;
    const int cIn = lane & 15;

    if (tid < 128) labR[tid] = labels[rowBase + tid];
    else           labC[tid - 128] = labels[colBase + (tid - 128)];

    // staging: 32 chunks of 1KB (8 rows x 128B). Wave handles 8.
    // lane i: subrow = i>>3, physical 16B-block = i&7, logical = (i&7)^subrow
    const int subrow = lane >> 3;
    const int swz = (lane & 7) ^ subrow;     // logical 16B-block index
    const unsigned char* gP[8];
    unsigned char* lP[8];
#pragma unroll
    for (int j = 0; j < 8; ++j) {
        const int c = wave * 8 + j;          // 0..31
        const int grow = (c < 16) ? (rowBase + c * 8 + subrow)
                                  : (colBase + (c - 16) * 8 + subrow);
        gP[j] = f8 + (size_t)grow * D + swz * 16;
        lP[j] = ((c < 16) ? (As + c * 1024) : (Bs + (c - 16) * 1024)) + lane * 16;
    }

    // fragment LDS offsets: row r, 32B k-group q = logical blocks 2q,2q+1
    // physical p = blk ^ (r&7)
    int aOff0[4], aOff1[4], bOff0[4], bOff1[4];
#pragma unroll
    for (int i = 0; i < 4; ++i) {
        const int rA = wr * 64 + i * 16 + cIn;
        aOff0[i] = rA * 128 + ((2 * q) ^ (rA & 7)) * 16;
        aOff1[i] = rA * 128 + ((2 * q + 1) ^ (rA & 7)) * 16;
        const int rB = wc * 64 + i * 16 + cIn;
        bOff0[i] = rB * 128 + ((2 * q) ^ (rB & 7)) * 16;
        bOff1[i] = rB * 128 + ((2 * q + 1) ^ (rB & 7)) * 16;
    }

    floatx4 acc[4][4] = {};

    const int KT = D >> 7;               // 8 iters of K=128
    for (int kt = 0; kt < KT; ++kt) {
        const int kOff = kt * 128;
        __syncthreads();                 // prev readers done (+labels at kt=0)
#pragma unroll
        for (int j = 0; j < 8; ++j)
            __builtin_amdgcn_global_load_lds((gvoid*)(gP[j] + kOff), (svoid*)lP[j], 16, 0, 0);
        __syncthreads();                 // stage landed (implicit vmcnt drain)

        intx8 a[4], b[4];
#pragma unroll
        for (int i = 0; i < 4; ++i) {
            intx4 lo = *(const intx4*)(As + aOff0[i]);
            intx4 hi = *(const intx4*)(As + aOff1[i]);
            a[i] = __builtin_shufflevector(lo, hi, 0, 1, 2, 3, 4, 5, 6, 7);
        }
#pragma unroll
        for (int i = 0; i < 4; ++i) {
            intx4 lo = *(const intx4*)(Bs + bOff0[i]);
            intx4 hi = *(const intx4*)(Bs + bOff1[i]);
            b[i] = __builtin_shufflevector(lo, hi, 0, 1, 2, 3, 4, 5, 6, 7);
        }
#pragma unroll
        for (int i = 0; i < 4; ++i)
#pragma unroll
            for (int j2 = 0; j2 < 4; ++j2)
                acc[i][j2] = __builtin_amdgcn_mfma_scale_f32_16x16x128_f8f6f4(
                    a[i], b[j2], acc[i][j2], 0, 0,       // cbsz=fp8, blgp=fp8
                    0, 0x7f7f7f7f,                       // opsel_a, scale_a (unity E8M0)
                    0, 0x7f7f7f7f);                      // opsel_b, scale_b
    }

    int rLabv[16];
#pragma unroll
    for (int mi = 0; mi < 4; ++mi)
#pragma unroll
        for (int rr = 0; rr < 4; ++rr)
            rLabv[mi * 4 + rr] = labR[wr * 64 + mi * 16 + q * 4 + rr];
    int cLabv[4];
#pragma unroll
    for (int ni = 0; ni < 4; ++ni)
        cLabv[ni] = labC[wc * 64 + ni * 16 + cIn];

    // ---- fp16 store: identical per-64-col-half layout to R13/R14 ----
    // virtual half-block hb = 2t + wc, virtual tid' = wr*64 + lane
    {
        half8* dst = (half8*)(simh + (size_t)(2 * t + wc) * 8192
                                   + (size_t)(wr * 64 + lane) * 64);
#pragma unroll
        for (int mi = 0; mi < 4; ++mi) {
            half8 h0, h1;
#pragma unroll
            for (int ni = 0; ni < 2; ++ni)
#pragma unroll
                for (int rr = 0; rr < 4; ++rr) {
                    h0[ni * 4 + rr] = (_Float16)acc[mi][ni][rr];
                    h1[ni * 4 + rr] = (_Float16)acc[mi][ni + 2][rr];
                }
            dst[mi * 2] = h0;
            dst[mi * 2 + 1] = h1;
        }
    }

    // ---- row stats (each wave: its 64 rows x its 64 cols partial) ----
#pragma unroll
    for (int mi = 0; mi < 4; ++mi)
#pragma unroll
        for (int rr = 0; rr < 4; ++rr) {
            const int rLoc = wr * 64 + mi * 16 + q * 4 + rr;
            const int rLab = rLabv[mi * 4 + rr];
            float vmin = 1e30f, vmax = -1e30f;
#pragma unroll
            for (int ni = 0; ni < 4; ++ni) {
                float s = acc[mi][ni][rr];
                if (rLab == cLabv[ni]) {
                    if (s < 1.0f - EPSV) vmin = fminf(vmin, s);
                } else {
                    vmax = fmaxf(vmax, s);
                }
            }
#pragma unroll
            for (int off = 8; off; off >>= 1) {
                vmin = fminf(vmin, __shfl_xor(vmin, off, 16));
                vmax = fmaxf(vmax, __shfl_xor(vmax, off, 16));
            }
            if (cIn == 0) {
                if (vmin < 1e30f) atomicMin(&minp_ord[rowBase + rLoc], f2ord(vmin));
                if (vmax > -1e30f) atomicMax(&maxn_ord[rowBase + rLoc], f2ord(vmax));
            }
        }

    // ---- col stats via symmetry (off-diagonal tiles only) ----
    if (rb != cb) {
#pragma unroll
        for (int ni = 0; ni < 4; ++ni) {
            const int cLab = cLabv[ni];
            float vmin = 1e30f, vmax = -1e30f;
#pragma unroll
            for (int mi = 0; mi < 4; ++mi)
#pragma unroll
                for (int rr = 0; rr < 4; ++rr) {
                    float s = acc[mi][ni][rr];
                    if (rLabv[mi * 4 + rr] == cLab) {
                        if (s < 1.0f - EPSV) vmin = fminf(vmin, s);
                    } else {
                        vmax = fmaxf(vmax, s);
                    }
                }
            vmin = fminf(vmin, __shfl_xor(vmin, 16, 64));
            vmin = fminf(vmin, __shfl_xor(vmin, 32, 64));
            vmax = fmaxf(vmax, __shfl_xor(vmax, 16, 64));
            vmax = fmaxf(vmax, __shfl_xor(vmax, 32, 64));
            if (q == 0) {
                const int cLoc = wc * 64 + ni * 16 + cIn;
                if (vmin < 1e30f) atomicMin(&minp_ord[colBase + cLoc], f2ord(vmin));
                if (vmax > -1e30f) atomicMax(&maxn_ord[colBase + cLoc], f2ord(vmax));
            }
        }
    }
}

// =====================================================================
// kernel 3 (unchanged R13/R14): pass 2, 528 blocks x 256 threads +
// fused final reduction behind the hierarchical RELAXED done-counter.
// =====================================================================
__global__ void __launch_bounds__(256)
k_sum2f(const _Float16* __restrict__ simh,
        const int* __restrict__ labels,
        const unsigned* __restrict__ minp_ord,
        const unsigned* __restrict__ maxn_ord,
        float* __restrict__ psum, float* __restrict__ nsum,
        unsigned* __restrict__ cnts,   // top @0; stripe s @ (1+s)*32
        float* __restrict__ out,
        int nb, int B, int NT) {
    __shared__ int labR[128], labC[128];
    __shared__ float mpR[128], mnR[128], mpC[128], mnC[128];
    __shared__ float red[4];
    __shared__ unsigned lastflag;

    int t = blockIdx.x;
    int rb = 0, rem = t;
    while (rem >= nb - rb) { rem -= nb - rb; ++rb; }
    const int cb = rb + rem;
    const int rowBase = rb * 128;

    const int tid = threadIdx.x;
    const int sub = tid >> 7;
    const int stid = tid & 127;
    const int wave = stid >> 6;
    const int lane = tid & 63;
    const int q = lane >> 4;
    const int cIn = lane & 15;
    const int colBase = cb * 128 + sub * 64;

    if (tid < 128) {
        labR[tid] = labels[rowBase + tid];
        mpR[tid] = ord2f(minp_ord[rowBase + tid]) - MARGIN;   // neg kept if s > this
        mnR[tid] = ord2f(maxn_ord[rowBase + tid]) + MARGIN;   // pos kept if s < this
    } else {
        const int j = tid - 128;
        labC[j] = labels[cb * 128 + j];
        mpC[j] = ord2f(minp_ord[cb * 128 + j]) - MARGIN;
        mnC[j] = ord2f(maxn_ord[cb * 128 + j]) + MARGIN;
    }
    __syncthreads();

    int cLabv[4];
    float mpCv[4], mnCv[4];
#pragma unroll
    for (int ni = 0; ni < 4; ++ni) {
        const int j = sub * 64 + ni * 16 + cIn;
        cLabv[ni] = labC[j];
        mpCv[ni] = mpC[j];
        mnCv[ni] = mnC[j];
    }

    const half8* src = (const half8*)(simh + (size_t)(2 * t + sub) * 8192 + (size_t)stid * 64);
    half8 hv[8];
#pragma unroll
    for (int v = 0; v < 8; ++v) hv[v] = src[v];

    float cps[4] = {}, cns[4] = {};
    const bool offd = (rb != cb);

#pragma unroll
    for (int mi = 0; mi < 4; ++mi)
#pragma unroll
        for (int rr = 0; rr < 4; ++rr) {
            const int rLoc = wave * 64 + mi * 16 + q * 4 + rr;
            const int rLab = labR[rLoc];
            const float gateN = mpR[rLoc];
            const float gateP = mnR[rLoc];
            float rp = 0.f, rn = 0.f;
#pragma unroll
            for (int ni = 0; ni < 4; ++ni) {
                const int idx = mi * 16 + ni * 4 + rr;
                const float s = (float)hv[idx >> 3][idx & 7];
                if (rLab == cLabv[ni]) {
                    if (s < 1.0f - EPSV) {
                        float ev = __expf(-SCALE_POS * (s - THRESH));
                        if (s < gateP) rp += ev;
                        if (offd && s < mnCv[ni]) cps[ni] += ev;
                    }
                } else {
                    float ev = __expf(SCALE_NEG * (s - THRESH));
                    if (s > gateN) rn += ev;
                    if (offd && s > mpCv[ni]) cns[ni] += ev;
                }
            }
#pragma unroll
            for (int off = 8; off; off >>= 1) {
                rp += __shfl_xor(rp, off, 16);
                rn += __shfl_xor(rn, off, 16);
            }
            if (cIn == 0) {
                if (rp != 0.f) atomicAdd(&psum[rowBase + rLoc], rp);
                if (rn != 0.f) atomicAdd(&nsum[rowBase + rLoc], rn);
            }
        }
    if (offd) {
#pragma unroll
        for (int ni = 0; ni < 4; ++ni) {
            cps[ni] += __shfl_xor(cps[ni], 16, 64);
            cps[ni] += __shfl_xor(cps[ni], 32, 64);
            cns[ni] += __shfl_xor(cns[ni], 16, 64);
            cns[ni] += __shfl_xor(cns[ni], 32, 64);
            if (q == 0) {
                const int cLoc = ni * 16 + cIn;
                if (cps[ni] != 0.f) atomicAdd(&psum[colBase + cLoc], cps[ni]);
                if (cns[ni] != 0.f) atomicAdd(&nsum[colBase + cLoc], cns[ni]);
            }
        }
    }

    // ---- hierarchical done-counter (all RELAXED — no fences) ----
    __syncthreads();
    if (tid == 0) {
        const unsigned stripe = (unsigned)blockIdx.x & 31u;
        const unsigned stripe_target = (unsigned)((NT - (int)stripe + 31) / 32);
        unsigned prev = __hip_atomic_fetch_add(&cnts[(1 + stripe) * 32], 1u,
                                               __ATOMIC_RELAXED, __HIP_MEMORY_SCOPE_AGENT);
        unsigned lf = 0u;
        if (prev == stripe_target - 1u) {
            unsigned ptop = __hip_atomic_fetch_add(&cnts[0], 1u,
                                                   __ATOMIC_RELAXED, __HIP_MEMORY_SCOPE_AGENT);
            lf = (ptop == 31u) ? 1u : 0u;
        }
        lastflag = lf;
    }
    __syncthreads();
    if (lastflag) {
        float a = 0.f;
        for (int i = tid; i < B; i += 256) {
            float pv = atomicAdd(&psum[i], 0.0f);   // coherent returning atomic
            float nv = atomicAdd(&nsum[i], 0.0f);
            if (pv > 0.f && nv > 0.f)
                a += log1pf(pv) * (1.0f / SCALE_POS) + log1pf(nv) * (1.0f / SCALE_NEG);
        }
#pragma unroll
        for (int off = 32; off; off >>= 1) a += __shfl_down(a, off, 64);
        if ((tid & 63) == 0) red[tid >> 6] = a;
        __syncthreads();
        if (tid == 0) out[0] = (red[0] + red[1] + red[2] + red[3]) / (float)B;
    }
}

extern "C" void kernel_launch(void* const* d_in, const int* in_sizes, int n_in,
                              void* d_out, int out_size, void* d_ws, size_t ws_size,
                              hipStream_t stream) {
    const float* feats = (const float*)d_in[0];
    const int* labels = (const int*)d_in[1];
    const int B = in_sizes[1];            // 4096
    const int D = in_sizes[0] / B;        // 1024
    const int nb = B / 128;               // 32
    const int NT = nb * (nb + 1) / 2;     // 528
    const int total4 = B * D / 4;

    char* ws = (char*)d_ws;
    unsigned char* f8 = (unsigned char*)ws;
    size_t off = (size_t)B * D;           // 4 MB fp8
    unsigned* minp = (unsigned*)(ws + off); off += (size_t)B * 4;
    unsigned* maxn = (unsigned*)(ws + off); off += (size_t)B * 4;
    float* psum = (float*)(ws + off); off += (size_t)B * 4;
    float* nsum = (float*)(ws + off); off += (size_t)B * 4;
    unsigned* cnts = (unsigned*)(ws + off); off += 8192;  // 2048 u32, zeroed by k_init
    _Float16* simh = (_Float16*)(ws + ((off + 255) & ~(size_t)255));
    float* outp = (float*)d_out;

    k_init<<<(total4 + 255) / 256, 256, 0, stream>>>(feats, f8, minp, maxn,
                                                     psum, nsum, cnts, total4, B);

    // 528 blocks x 256 thr — full-tile MX-fp8 GEMM, XCD-swizzled (R19)
    k_gemm_h<<<NT, 256, 0, stream>>>(f8, labels, minp, maxn, simh, D, nb);

    // 528 blocks x 256 thr, hierarchical relaxed done-counter
    k_sum2f<<<NT, 256, 0, stream>>>(simh, labels, minp, maxn, psum, nsum,
                                    cnts, outp, nb, B, NT);
}

// Round 4
// 134.668 us; speedup vs baseline: 1.0368x; 1.0285x over previous
//
#include <hip/hip_runtime.h>

typedef _Float16 half8 __attribute__((ext_vector_type(8)));
typedef float floatx4 __attribute__((ext_vector_type(4)));
typedef int intx4 __attribute__((ext_vector_type(4)));
typedef int intx8 __attribute__((ext_vector_type(8)));
typedef __attribute__((address_space(1))) const void gvoid;
typedef __attribute__((address_space(3))) void svoid;

#define SCALE_POS 2.0f
#define SCALE_NEG 40.0f
#define THRESH 0.5f
#define MARGIN 0.1f
#define EPSV 1e-5f

// ---- kernel 1: fp32 -> fp8 e4m3 (OCP, RNE via HW cvt) + out zero ----
__global__ void k_init(const float* __restrict__ feats,
                       unsigned char* __restrict__ f8,
                       float* __restrict__ out,
                       int total4) {
    int i = blockIdx.x * blockDim.x + threadIdx.x;
    if (i < total4) {
        float4 v = ((const float4*)feats)[i];
        int w = 0;
        w = __builtin_amdgcn_cvt_pk_fp8_f32(v.x, v.y, w, false);  // bytes 0,1
        w = __builtin_amdgcn_cvt_pk_fp8_f32(v.z, v.w, w, true);   // bytes 2,3
        ((int*)f8)[i] = w;
    }
    if (i == 0) out[0] = 0.f;
}

// =====================================================================
// kernel 2 (R20): MX-fp8 symmetric GEMM over FULL 128x128 tiles.
// 528 blocks x 256 thr (4 waves in a 2x2 grid of 64x64 sub-tiles).
// K-loop/tile math identical to R19 (verified).
//
// CHANGE vs R19 (46.5 us, invariant across R14/R17/R18/R19 K-loop
// restructurings): the epilogue's ~270K device-scope atomicMin/Max
// RMWs (FETCH_SIZE 17.3 MB = 270K x 64B line round-trips on a 512-line
// array -> coherence-point ping-pong) are replaced by UNIQUE-WRITER
// partial stores: pmin/pmax are [64][B] f32; for row r in block R the
// slots {2*cb+wc : cb>=R} (row-side) and {2*rb+wr : rb<R} (col-side of
// tiles (rb,R)) partition [0,64) exactly -> every slot written once,
// plain store, L2-merged full lines, zero contention, no init needed.
// A tiny k_stats kernel reduces the 2 MB of partials into gate arrays.
// =====================================================================
__global__ void __launch_bounds__(256, 4)
k_gemm_h(const unsigned char* __restrict__ f8,
         const int* __restrict__ labels,
         float* __restrict__ pmin,     // [64][B] partial min-pos
         float* __restrict__ pmax,     // [64][B] partial max-neg
         _Float16* __restrict__ simh,
         int D, int nb) {      // D = 1024 elements = 1024 bytes/row
    __shared__ __align__(16) unsigned char As[128 * 128];  // 16 KB
    __shared__ __align__(16) unsigned char Bs[128 * 128];  // 16 KB
    __shared__ int labR[128], labC[128];

    const int Bsz = nb * 128;

    // bijective XCD-aware swizzle: 528 tiles = 8 XCDs x 66
    const int bid0 = blockIdx.x;
    const int t = (bid0 & 7) * 66 + (bid0 >> 3);
    int rb = 0, rem = t;
    while (rem >= nb - rb) { rem -= nb - rb; ++rb; }
    const int cb = rb + rem;
    const int rowBase = rb * 128;
    const int colBase = cb * 128;

    const int tid = threadIdx.x;        // 0..255
    const int lane = tid & 63;
    const int wave = tid >> 6;          // 0..3
    const int wr = wave >> 1;           // row half of output tile
    const int wc = wave & 1;            // col half of output tile
    const int q = lane >> 4;
    const int cIn = lane & 15;

    if (tid < 128) labR[tid] = labels[rowBase + tid];
    else           labC[tid - 128] = labels[colBase + (tid - 128)];

    // staging: 32 chunks of 1KB (8 rows x 128B). Wave handles 8.
    const int subrow = lane >> 3;
    const int swz = (lane & 7) ^ subrow;     // logical 16B-block index
    const unsigned char* gP[8];
    unsigned char* lP[8];
#pragma unroll
    for (int j = 0; j < 8; ++j) {
        const int c = wave * 8 + j;          // 0..31
        const int grow = (c < 16) ? (rowBase + c * 8 + subrow)
                                  : (colBase + (c - 16) * 8 + subrow);
        gP[j] = f8 + (size_t)grow * D + swz * 16;
        lP[j] = ((c < 16) ? (As + c * 1024) : (Bs + (c - 16) * 1024)) + lane * 16;
    }

    // fragment LDS offsets: row r, 32B k-group q = logical blocks 2q,2q+1
    // physical p = blk ^ (r&7)
    int aOff0[4], aOff1[4], bOff0[4], bOff1[4];
#pragma unroll
    for (int i = 0; i < 4; ++i) {
        const int rA = wr * 64 + i * 16 + cIn;
        aOff0[i] = rA * 128 + ((2 * q) ^ (rA & 7)) * 16;
        aOff1[i] = rA * 128 + ((2 * q + 1) ^ (rA & 7)) * 16;
        const int rB = wc * 64 + i * 16 + cIn;
        bOff0[i] = rB * 128 + ((2 * q) ^ (rB & 7)) * 16;
        bOff1[i] = rB * 128 + ((2 * q + 1) ^ (rB & 7)) * 16;
    }

    floatx4 acc[4][4] = {};

    const int KT = D >> 7;               // 8 iters of K=128
    for (int kt = 0; kt < KT; ++kt) {
        const int kOff = kt * 128;
        __syncthreads();                 // prev readers done (+labels at kt=0)
#pragma unroll
        for (int j = 0; j < 8; ++j)
            __builtin_amdgcn_global_load_lds((gvoid*)(gP[j] + kOff), (svoid*)lP[j], 16, 0, 0);
        __syncthreads();                 // stage landed (implicit vmcnt drain)

        intx8 a[4], b[4];
#pragma unroll
        for (int i = 0; i < 4; ++i) {
            intx4 lo = *(const intx4*)(As + aOff0[i]);
            intx4 hi = *(const intx4*)(As + aOff1[i]);
            a[i] = __builtin_shufflevector(lo, hi, 0, 1, 2, 3, 4, 5, 6, 7);
        }
#pragma unroll
        for (int i = 0; i < 4; ++i) {
            intx4 lo = *(const intx4*)(Bs + bOff0[i]);
            intx4 hi = *(const intx4*)(Bs + bOff1[i]);
            b[i] = __builtin_shufflevector(lo, hi, 0, 1, 2, 3, 4, 5, 6, 7);
        }
#pragma unroll
        for (int i = 0; i < 4; ++i)
#pragma unroll
            for (int j2 = 0; j2 < 4; ++j2)
                acc[i][j2] = __builtin_amdgcn_mfma_scale_f32_16x16x128_f8f6f4(
                    a[i], b[j2], acc[i][j2], 0, 0,       // cbsz=fp8, blgp=fp8
                    0, 0x7f7f7f7f,                       // opsel_a, scale_a (unity E8M0)
                    0, 0x7f7f7f7f);                      // opsel_b, scale_b
    }

    int rLabv[16];
#pragma unroll
    for (int mi = 0; mi < 4; ++mi)
#pragma unroll
        for (int rr = 0; rr < 4; ++rr)
            rLabv[mi * 4 + rr] = labR[wr * 64 + mi * 16 + q * 4 + rr];
    int cLabv[4];
#pragma unroll
    for (int ni = 0; ni < 4; ++ni)
        cLabv[ni] = labC[wc * 64 + ni * 16 + cIn];

    // ---- fp16 store: identical per-64-col-half layout to R13/R14 ----
    {
        half8* dst = (half8*)(simh + (size_t)(2 * t + wc) * 8192
                                   + (size_t)(wr * 64 + lane) * 64);
#pragma unroll
        for (int mi = 0; mi < 4; ++mi) {
            half8 h0, h1;
#pragma unroll
            for (int ni = 0; ni < 2; ++ni)
#pragma unroll
                for (int rr = 0; rr < 4; ++rr) {
                    h0[ni * 4 + rr] = (_Float16)acc[mi][ni][rr];
                    h1[ni * 4 + rr] = (_Float16)acc[mi][ni + 2][rr];
                }
            dst[mi * 2] = h0;
            dst[mi * 2 + 1] = h1;
        }
    }

    // ---- row stats partials: slot (2*cb+wc), plain stores ----
    {
        float* pmnRow = pmin + (size_t)(2 * cb + wc) * Bsz + rowBase;
        float* pmxRow = pmax + (size_t)(2 * cb + wc) * Bsz + rowBase;
#pragma unroll
        for (int mi = 0; mi < 4; ++mi)
#pragma unroll
            for (int rr = 0; rr < 4; ++rr) {
                const int rLoc = wr * 64 + mi * 16 + q * 4 + rr;
                const int rLab = rLabv[mi * 4 + rr];
                float vmin = 1e30f, vmax = -1e30f;
#pragma unroll
                for (int ni = 0; ni < 4; ++ni) {
                    float s = acc[mi][ni][rr];
                    if (rLab == cLabv[ni]) {
                        if (s < 1.0f - EPSV) vmin = fminf(vmin, s);
                    } else {
                        vmax = fmaxf(vmax, s);
                    }
                }
#pragma unroll
                for (int off = 8; off; off >>= 1) {
                    vmin = fminf(vmin, __shfl_xor(vmin, off, 16));
                    vmax = fmaxf(vmax, __shfl_xor(vmax, off, 16));
                }
                if (cIn == 0) {
                    pmnRow[rLoc] = vmin;
                    pmxRow[rLoc] = vmax;
                }
            }
    }

    // ---- col stats partials via symmetry (off-diag only): slot (2*rb+wr) ----
    if (rb != cb) {
        float* pmnCol = pmin + (size_t)(2 * rb + wr) * Bsz + colBase;
        float* pmxCol = pmax + (size_t)(2 * rb + wr) * Bsz + colBase;
#pragma unroll
        for (int ni = 0; ni < 4; ++ni) {
            const int cLab = cLabv[ni];
            float vmin = 1e30f, vmax = -1e30f;
#pragma unroll
            for (int mi = 0; mi < 4; ++mi)
#pragma unroll
                for (int rr = 0; rr < 4; ++rr) {
                    float s = acc[mi][ni][rr];
                    if (rLabv[mi * 4 + rr] == cLab) {
                        if (s < 1.0f - EPSV) vmin = fminf(vmin, s);
                    } else {
                        vmax = fmaxf(vmax, s);
                    }
                }
            vmin = fminf(vmin, __shfl_xor(vmin, 16, 64));
            vmin = fminf(vmin, __shfl_xor(vmin, 32, 64));
            vmax = fmaxf(vmax, __shfl_xor(vmax, 16, 64));
            vmax = fmaxf(vmax, __shfl_xor(vmax, 32, 64));
            if (q == 0) {
                const int cLoc = wc * 64 + ni * 16 + cIn;
                pmnCol[cLoc] = vmin;
                pmxCol[cLoc] = vmax;
            }
        }
    }
}

// =====================================================================
// kernel 2.5: reduce stat partials -> gate arrays (pre-offset by MARGIN)
// gateN[r] = min_pos - MARGIN (neg kept if s > gateN)
// gateP[r] = max_neg + MARGIN (pos kept if s < gateP)
// 16 blocks x 256 thr; coalesced (consecutive r per k-slot).
// =====================================================================
__global__ void __launch_bounds__(256)
k_stats(const float* __restrict__ pmin, const float* __restrict__ pmax,
        float* __restrict__ gateN, float* __restrict__ gateP, int B) {
    const int r = blockIdx.x * 256 + threadIdx.x;
    float mn = 1e30f, mx = -1e30f;
    for (int k = 0; k < 64; ++k) {
        mn = fminf(mn, pmin[(size_t)k * B + r]);
        mx = fmaxf(mx, pmax[(size_t)k * B + r]);
    }
    gateN[r] = mn - MARGIN;
    gateP[r] = mx + MARGIN;
}

// =====================================================================
// kernel 3 (R20): pass 2, 528 blocks x 256 threads. Gated exp sums ->
// unique-writer partial arrays psP/psN [64][B] (same slot partition as
// k_gemm). No atomics, no done-counter, no ord decode.
// =====================================================================
__global__ void __launch_bounds__(256)
k_sum2f(const _Float16* __restrict__ simh,
        const int* __restrict__ labels,
        const float* __restrict__ gateN,
        const float* __restrict__ gateP,
        float* __restrict__ psP, float* __restrict__ psN,
        int nb, int B) {
    __shared__ int labR[128], labC[128];
    __shared__ float gNR[128], gPR[128], gNC[128], gPC[128];

    int t = blockIdx.x;
    int rb = 0, rem = t;
    while (rem >= nb - rb) { rem -= nb - rb; ++rb; }
    const int cb = rb + rem;
    const int rowBase = rb * 128;

    const int tid = threadIdx.x;
    const int sub = tid >> 7;           // 0..1 : col half
    const int stid = tid & 127;
    const int wave = stid >> 6;         // 0..1 : row half within sub
    const int lane = tid & 63;
    const int q = lane >> 4;
    const int cIn = lane & 15;
    const int colBase = cb * 128 + sub * 64;

    if (tid < 128) {
        labR[tid] = labels[rowBase + tid];
        gNR[tid] = gateN[rowBase + tid];
        gPR[tid] = gateP[rowBase + tid];
    } else {
        const int j = tid - 128;
        labC[j] = labels[cb * 128 + j];
        gNC[j] = gateN[cb * 128 + j];
        gPC[j] = gateP[cb * 128 + j];
    }
    __syncthreads();

    int cLabv[4];
    float gNCv[4], gPCv[4];
#pragma unroll
    for (int ni = 0; ni < 4; ++ni) {
        const int j = sub * 64 + ni * 16 + cIn;
        cLabv[ni] = labC[j];
        gNCv[ni] = gNC[j];
        gPCv[ni] = gPC[j];
    }

    const half8* src = (const half8*)(simh + (size_t)(2 * t + sub) * 8192 + (size_t)stid * 64);
    half8 hv[8];
#pragma unroll
    for (int v = 0; v < 8; ++v) hv[v] = src[v];

    float cps[4] = {}, cns[4] = {};
    const bool offd = (rb != cb);

    float* psPRow = psP + (size_t)(2 * cb + sub) * B + rowBase;
    float* psNRow = psN + (size_t)(2 * cb + sub) * B + rowBase;

#pragma unroll
    for (int mi = 0; mi < 4; ++mi)
#pragma unroll
        for (int rr = 0; rr < 4; ++rr) {
            const int rLoc = wave * 64 + mi * 16 + q * 4 + rr;
            const int rLab = labR[rLoc];
            const float gn = gNR[rLoc];
            const float gp = gPR[rLoc];
            float rp = 0.f, rn = 0.f;
#pragma unroll
            for (int ni = 0; ni < 4; ++ni) {
                const int idx = mi * 16 + ni * 4 + rr;
                const float s = (float)hv[idx >> 3][idx & 7];
                if (rLab == cLabv[ni]) {
                    if (s < 1.0f - EPSV) {
                        float ev = __expf(-SCALE_POS * (s - THRESH));
                        if (s < gp) rp += ev;
                        if (offd && s < gPCv[ni]) cps[ni] += ev;
                    }
                } else {
                    float ev = __expf(SCALE_NEG * (s - THRESH));
                    if (s > gn) rn += ev;
                    if (offd && s > gNCv[ni]) cns[ni] += ev;
                }
            }
#pragma unroll
            for (int off = 8; off; off >>= 1) {
                rp += __shfl_xor(rp, off, 16);
                rn += __shfl_xor(rn, off, 16);
            }
            if (cIn == 0) {
                psPRow[rLoc] = rp;      // always write (unique slot)
                psNRow[rLoc] = rn;
            }
        }
    if (offd) {
        float* psPCol = psP + (size_t)(2 * rb + wave) * B + colBase;
        float* psNCol = psN + (size_t)(2 * rb + wave) * B + colBase;
#pragma unroll
        for (int ni = 0; ni < 4; ++ni) {
            cps[ni] += __shfl_xor(cps[ni], 16, 64);
            cps[ni] += __shfl_xor(cps[ni], 32, 64);
            cns[ni] += __shfl_xor(cns[ni], 16, 64);
            cns[ni] += __shfl_xor(cns[ni], 32, 64);
            if (q == 0) {
                const int cLoc = ni * 16 + cIn;
                psPCol[cLoc] = cps[ni];
                psNCol[cLoc] = cns[ni];
            }
        }
    }
}

// =====================================================================
// kernel 4: final reduce. 16 blocks x 256 thr; each thread one row:
// P = sum_k psP[k][r], N = sum_k psN[k][r]; loss terms; block reduce;
// one atomicAdd per block to out[0] (zeroed by k_init).
// =====================================================================
__global__ void __launch_bounds__(256)
k_final(const float* __restrict__ psP, const float* __restrict__ psN,
        float* __restrict__ out, int B) {
    __shared__ float red[4];
    const int r = blockIdx.x * 256 + threadIdx.x;
    float P = 0.f, N = 0.f;
    for (int k = 0; k < 64; ++k) {
        P += psP[(size_t)k * B + r];
        N += psN[(size_t)k * B + r];
    }
    float a = (P > 0.f && N > 0.f)
                  ? log1pf(P) * (1.0f / SCALE_POS) + log1pf(N) * (1.0f / SCALE_NEG)
                  : 0.f;
#pragma unroll
    for (int off = 32; off; off >>= 1) a += __shfl_down(a, off, 64);
    const int tid = threadIdx.x;
    if ((tid & 63) == 0) red[tid >> 6] = a;
    __syncthreads();
    if (tid == 0)
        atomicAdd(out, (red[0] + red[1] + red[2] + red[3]) / (float)B);
}

extern "C" void kernel_launch(void* const* d_in, const int* in_sizes, int n_in,
                              void* d_out, int out_size, void* d_ws, size_t ws_size,
                              hipStream_t stream) {
    const float* feats = (const float*)d_in[0];
    const int* labels = (const int*)d_in[1];
    const int B = in_sizes[1];            // 4096
    const int D = in_sizes[0] / B;        // 1024
    const int nb = B / 128;               // 32
    const int NT = nb * (nb + 1) / 2;     // 528
    const int total4 = B * D / 4;

    char* ws = (char*)d_ws;
    unsigned char* f8 = (unsigned char*)ws;
    size_t off = (size_t)B * D;           // 4 MB fp8
    float* pmin = (float*)(ws + off); off += (size_t)64 * B * 4;   // 1 MB
    float* pmax = (float*)(ws + off); off += (size_t)64 * B * 4;   // 1 MB
    float* psP  = (float*)(ws + off); off += (size_t)64 * B * 4;   // 1 MB
    float* psN  = (float*)(ws + off); off += (size_t)64 * B * 4;   // 1 MB
    float* gateN = (float*)(ws + off); off += (size_t)B * 4;
    float* gateP = (float*)(ws + off); off += (size_t)B * 4;
    _Float16* simh = (_Float16*)(ws + ((off + 255) & ~(size_t)255));
    float* outp = (float*)d_out;

    k_init<<<(total4 + 255) / 256, 256, 0, stream>>>(feats, f8, outp, total4);

    // 528 blocks x 256 thr — full-tile MX-fp8 GEMM, partial-slot stats (R20)
    k_gemm_h<<<NT, 256, 0, stream>>>(f8, labels, pmin, pmax, simh, D, nb);

    // gate reduce: 16 blocks
    k_stats<<<B / 256, 256, 0, stream>>>(pmin, pmax, gateN, gateP, B);

    // pass 2: 528 blocks x 256 thr, partial-slot sums
    k_sum2f<<<NT, 256, 0, stream>>>(simh, labels, gateN, gateP, psP, psN, nb, B);

    // final: 16 blocks, one atomic each
    k_final<<<B / 256, 256, 0, stream>>>(psP, psN, outp, B);
}